// Round 18
// baseline (333.913 us; speedup 1.0000x reference)
//
#include <hip/hip_runtime.h>
#include <hip/hip_bf16.h>
#include <math.h>

typedef __hip_bfloat16 bf16;
typedef __attribute__((ext_vector_type(8))) short short8;   // 8 bf16 = 4 VGPRs
typedef __attribute__((ext_vector_type(4))) float f32x4;

#define DEV __device__ __forceinline__

// problem constants
constexpr int CB = 8, CN = 1024, CD = 768, CH = 12, CK = 64, CF = 3072;
constexpr int ROWS = CB * CN;  // 8192

// ---------------------------------------------------------------- utilities
DEV void gload_lds16(const void* g, void* l) {
  __builtin_amdgcn_global_load_lds(
      (const __attribute__((address_space(1))) void*)g,
      (__attribute__((address_space(3))) void*)l, 16, 0, 0);
}

// ------------------------------------------------- weight prep (T + cast)
// four 768x768 fp32 [R][C] -> bf16 [C][R]; z selects matrix; wq scaled 1/8.
__global__ __launch_bounds__(256) void transpose4_f32_bf16(
    const float* __restrict__ s0, const float* __restrict__ s1,
    const float* __restrict__ s2, const float* __restrict__ s3,
    bf16* __restrict__ d0, bf16* __restrict__ d1, bf16* __restrict__ d2,
    bf16* __restrict__ d3) {
  __shared__ float tile[32][33];
  const int z = blockIdx.z;
  const float* in = (z == 0) ? s0 : (z == 1) ? s1 : (z == 2) ? s2 : s3;
  bf16* out = (z == 0) ? d0 : (z == 1) ? d1 : (z == 2) ? d2 : d3;
  const float scale = (z == 0) ? 0.125f : 1.f;
  const int R = 768, C = 768;
  const int tx = threadIdx.x & 31, ty = threadIdx.x >> 5;  // 32 x 8
  const int c0 = blockIdx.x * 32, r0 = blockIdx.y * 32;
#pragma unroll
  for (int i = 0; i < 4; ++i)
    tile[ty + i * 8][tx] = in[(size_t)(r0 + ty + i * 8) * C + c0 + tx];
  __syncthreads();
#pragma unroll
  for (int i = 0; i < 4; ++i)
    out[(size_t)(c0 + ty + i * 8) * R + r0 + tx] =
        __float2bfloat16(tile[tx][ty + i * 8] * scale);
}

__global__ __launch_bounds__(256) void transpose_f32_bf16(
    const float* __restrict__ in, bf16* __restrict__ out, int R, int C,
    float scale) {
  __shared__ float tile[32][33];
  const int tx = threadIdx.x & 31, ty = threadIdx.x >> 5;  // 32 x 8
  const int c0 = blockIdx.x * 32, r0 = blockIdx.y * 32;
#pragma unroll
  for (int i = 0; i < 4; ++i)
    tile[ty + i * 8][tx] = in[(size_t)(r0 + ty + i * 8) * C + c0 + tx];
  __syncthreads();
#pragma unroll
  for (int i = 0; i < 4; ++i)
    out[(size_t)(c0 + ty + i * 8) * R + r0 + tx] =
        __float2bfloat16(tile[tx][ty + i * 8] * scale);
}

// ---------------------------------------------------------------- LayerNorm
__global__ __launch_bounds__(256) void ln_bf16(
    const float* __restrict__ in, const float* __restrict__ gamma,
    const float* __restrict__ beta, bf16* __restrict__ out) {
  const int row = blockIdx.x;
  const int tid = threadIdx.x;
  const float* x = in + (size_t)row * CD;
  const float v0 = x[tid], v1 = x[tid + 256], v2 = x[tid + 512];
  float s = v0 + v1 + v2;
  float q = v0 * v0 + v1 * v1 + v2 * v2;
#pragma unroll
  for (int off = 32; off > 0; off >>= 1) {
    s += __shfl_xor(s, off);
    q += __shfl_xor(q, off);
  }
  __shared__ float sm[8];
  const int w = tid >> 6, l = tid & 63;
  if (l == 0) { sm[w] = s; sm[4 + w] = q; }
  __syncthreads();
  s = sm[0] + sm[1] + sm[2] + sm[3];
  q = sm[4] + sm[5] + sm[6] + sm[7];
  const float mean = s * (1.f / CD);
  const float var = q * (1.f / CD) - mean * mean;
  const float rs = rsqrtf(var + 1e-5f);
  bf16* o = out + (size_t)row * CD;
  o[tid]       = __float2bfloat16((v0 - mean) * rs * gamma[tid]       + beta[tid]);
  o[tid + 256] = __float2bfloat16((v1 - mean) * rs * gamma[tid + 256] + beta[tid + 256]);
  o[tid + 512] = __float2bfloat16((v2 - mean) * rs * gamma[tid + 512] + beta[tid + 512]);
}

// ------------------------------------------------- 128x128 GEMM (m97 proven)
// C[M,N] = A[M,K]*Bt[N,K]^T, BK=32, 4 waves (2x2), wave 64x64. 3-5 blocks/CU
// co-residency; smooth grid fill (R18: used for QKV to kill the 256² kernel's
// 288-block 2-round tail). 1D grid + XCD swizzle (grid % 8 == 0).
// EPI 0: QKV scatter (+bias; col < 1536: Q/K -> [B,H,N,K]; >= 1536: V via
//        SWAPPED MFMA operands -> coalesced Vt [B,H,K,N]; wq/bq pre-scaled).
// EPI 1: +bias +resid -> fp32 (ld=CD).
template <int EPI>
__global__ __launch_bounds__(256) void gemm128_kernel(
    const bf16* __restrict__ A, const bf16* __restrict__ Bt, int Kd, int nbx,
    float* __restrict__ outF, bf16* __restrict__ dst0, bf16* __restrict__ dst1,
    bf16* __restrict__ dst2, const float* __restrict__ bias0,
    const float* __restrict__ bias1, const float* __restrict__ bias2,
    const float* __restrict__ resid) {
  __shared__ __align__(16) bf16 As[128 * 32];
  __shared__ __align__(16) bf16 Bs[128 * 32];
  const int tid = threadIdx.x;
  const int w = tid >> 6, l = tid & 63;
  const int wr = w >> 1, wc = w & 1;
  const int l15 = l & 15, lg = l >> 4;
  const int L = blockIdx.x;
  const int cpx = gridDim.x >> 3;
  const int g = (L & 7) * cpx + (L >> 3);
  const int by = g / nbx, bx = g - by * nbx;
  const int rowBase = by * 128;
  const int colBase = bx * 128;
  const bool vswap = (EPI == 0) && (colBase >= 2 * CD);

  f32x4 acc[4][4];
#pragma unroll
  for (int i = 0; i < 4; ++i)
#pragma unroll
    for (int j = 0; j < 4; ++j)
#pragma unroll
      for (int r = 0; r < 4; ++r) acc[i][j][r] = 0.f;

  for (int k0 = 0; k0 < Kd; k0 += 32) {
    __syncthreads();
#pragma unroll
    for (int i = 0; i < 2; ++i) {
      const int c = w * 128 + i * 64 + l;       // 16B chunk id, 0..511
      const int r = c >> 2, cc = c & 3;         // tile row, 8-elem col chunk
      gload_lds16(A + (size_t)(rowBase + r) * Kd + k0 + cc * 8,
                  (void*)&As[(w * 128 + i * 64) * 8]);
      gload_lds16(Bt + (size_t)(colBase + r) * Kd + k0 + cc * 8,
                  (void*)&Bs[(w * 128 + i * 64) * 8]);
    }
    __syncthreads();
    short8 af[4], bfr[4];
#pragma unroll
    for (int fm = 0; fm < 4; ++fm)
      af[fm] = *reinterpret_cast<const short8*>(
          &As[(wr * 64 + fm * 16 + l15) * 32 + lg * 8]);
#pragma unroll
    for (int fn = 0; fn < 4; ++fn)
      bfr[fn] = *reinterpret_cast<const short8*>(
          &Bs[(wc * 64 + fn * 16 + l15) * 32 + lg * 8]);
    if (vswap) {
#pragma unroll
      for (int fm = 0; fm < 4; ++fm)
#pragma unroll
        for (int fn = 0; fn < 4; ++fn)
          acc[fm][fn] = __builtin_amdgcn_mfma_f32_16x16x32_bf16(
              bfr[fn], af[fm], acc[fm][fn], 0, 0, 0);
    } else {
#pragma unroll
      for (int fm = 0; fm < 4; ++fm)
#pragma unroll
        for (int fn = 0; fn < 4; ++fn)
          acc[fm][fn] = __builtin_amdgcn_mfma_f32_16x16x32_bf16(
              af[fm], bfr[fn], acc[fm][fn], 0, 0, 0);
    }
  }

  const int mrow0 = rowBase + wr * 64;
  const int ncol0 = colBase + wc * 64;
  if constexpr (EPI == 0) {
    if (vswap) {
      // swapped: lane axis = token row, reg axis = hk col (verified R7-R17)
#pragma unroll
      for (int fm = 0; fm < 4; ++fm) {
        const int n = mrow0 + fm * 16 + l15;
        const int b = n >> 10, nn = n & 1023;
#pragma unroll
        for (int fn = 0; fn < 4; ++fn) {
#pragma unroll
          for (int fr = 0; fr < 4; ++fr) {
            const int hk = (ncol0 - 2 * CD) + fn * 16 + lg * 4 + fr;
            const float v = acc[fm][fn][fr] + bias2[hk];
            const int h = hk >> 6, kk = hk & 63;
            dst2[((size_t)(b * CH + h) * CK + kk) * CN + nn] = __float2bfloat16(v);
          }
        }
      }
    } else {
#pragma unroll
      for (int fm = 0; fm < 4; ++fm) {
#pragma unroll
        for (int fn = 0; fn < 4; ++fn) {
          const int col = ncol0 + fn * 16 + l15;
          const int which = col / CD;  // 0=Q 1=K (128-tiles never straddle)
          const int hk = col - which * CD;
          const float bias = (which == 0) ? bias0[hk] * 0.125f : bias1[hk];
          bf16* dst = (which == 0) ? dst0 : dst1;
          const int h = hk >> 6, kk = hk & 63;
#pragma unroll
          for (int fr = 0; fr < 4; ++fr) {
            const int row = mrow0 + fm * 16 + lg * 4 + fr;
            const int b = row >> 10, n = row & 1023;
            dst[(((size_t)(b * CH + h)) * CN + n) * CK + kk] =
                __float2bfloat16(acc[fm][fn][fr] + bias);
          }
        }
      }
    }
  } else {  // EPI == 1: +bias +resid -> fp32
#pragma unroll
    for (int fm = 0; fm < 4; ++fm) {
#pragma unroll
      for (int fn = 0; fn < 4; ++fn) {
        const int col = ncol0 + fn * 16 + l15;
#pragma unroll
        for (int fr = 0; fr < 4; ++fr) {
          const int row = mrow0 + fm * 16 + lg * 4 + fr;
          float v = acc[fm][fn][fr];
          v += bias0[col] + resid[(size_t)row * CD + col];
          outF[(size_t)row * CD + col] = v;
        }
      }
    }
  }
}

// ------------------------------------------- 256x256 GEMM, thin barriers
// R13/R17 proven: 4-phase, VGPR-112 no-spill, 2 barriers/K-tile. Used for
// MLP1 (384 blocks). Stage slots: p0 A(t+1)h0, p1 A(t+1)h1, p2 B(t+2)h0,
// p3 B(t+2)h1. Mid-barrier after ph0 MFMA; tile-end vmcnt(4)+barrier.
// t==NT-2: vmcnt(0). T2 swizzle: inverse-swz global source + swz ds_read.
template <int EPI>
__global__ __launch_bounds__(512, 2) void gemm256_kernel(
    const bf16* __restrict__ A, const bf16* __restrict__ Bt, int Kd, int nbx,
    bf16* __restrict__ dst0, const float* __restrict__ bias0) {
  __shared__ __align__(16) bf16 As[2][2][128 * 64];  // 64 KB
  __shared__ __align__(16) bf16 Bs[2][2][128 * 64];  // 64 KB

  const int tid = threadIdx.x;
  const int w = tid >> 6, l = tid & 63;
  const int wr = w >> 2, wc = w & 3;  // 2 x 4 wave grid
  const int l15 = l & 15, lg = l >> 4;

  const int L = blockIdx.x;
  const int cpx = gridDim.x >> 3;
  const int g = (L & 7) * cpx + (L >> 3);   // XCD swizzle (grid % 8 == 0)
  const int by = g / nbx, bx = g - by * nbx;
  const int rowBase = by * 256, colBase = bx * 256;
  const int NT = Kd >> 6;

  auto stage = [&](int t, int q) {
    const int buf = t & 1;
    const int half = q & 1;
    const bf16* src = (q < 2) ? A : Bt;
    const int base = ((q < 2) ? rowBase : colBase) + half * 128;
    const int k0 = t * 64;
    bf16* lds = (q < 2) ? &As[buf][half][0] : &Bs[buf][half][0];
#pragma unroll
    for (int i = 0; i < 2; ++i) {
      const int s = i * 512 + tid;           // 16B slot 0..1023
      const int row = s >> 3, c16 = s & 7;
      const int gc16 = c16 ^ (row & 7);      // inverse swizzle on source
      gload_lds16(src + (size_t)(base + row) * Kd + k0 + gc16 * 8,
                  (void*)&lds[(i * 512 + w * 64) * 8]);
    }
  };
  auto read_a = [&](int buf, int m, int kh) -> short8 {
    const int row = m * 16 + l15;
    const int c16 = (kh * 4 + lg) ^ (l15 & 7);  // swizzled read
    return *reinterpret_cast<const short8*>(&As[buf][wr][row * 64 + c16 * 8]);
  };
  auto read_b = [&](int buf, int n, int kh) -> short8 {
    const int c = wc * 64 + n * 16 + l15;
    const int half = c >> 7, row = c & 127;
    const int c16 = (kh * 4 + lg) ^ (l15 & 7);
    return *reinterpret_cast<const short8*>(&Bs[buf][half][row * 64 + c16 * 8]);
  };

  f32x4 acc[8][4];
#pragma unroll
  for (int m = 0; m < 8; ++m)
#pragma unroll
    for (int n = 0; n < 4; ++n)
#pragma unroll
      for (int r = 0; r < 4; ++r) acc[m][n][r] = 0.f;

  stage(0, 0); stage(0, 1); stage(0, 2); stage(0, 3);
  stage(1, 2); stage(1, 3);
  asm volatile("s_waitcnt vmcnt(4)" ::: "memory");
  __builtin_amdgcn_s_barrier();

  short8 bfrag[4][2];
  for (int t = 0; t < NT; ++t) {
    const int buf = t & 1;
#pragma unroll
    for (int p = 0; p < 4; ++p) {
      short8 afr[2][2];
      if (p == 0) {
#pragma unroll
        for (int n = 0; n < 4; ++n)
#pragma unroll
          for (int kh = 0; kh < 2; ++kh) bfrag[n][kh] = read_b(buf, n, kh);
      }
#pragma unroll
      for (int mm = 0; mm < 2; ++mm)
#pragma unroll
        for (int kh = 0; kh < 2; ++kh) afr[mm][kh] = read_a(buf, 2 * p + mm, kh);
      if (p == 0 && t + 1 < NT) stage(t + 1, 0);
      if (p == 1 && t + 1 < NT) stage(t + 1, 1);
      if (p == 2 && t + 2 < NT) stage(t + 2, 2);
      if (p == 3 && t + 2 < NT) stage(t + 2, 3);
      __builtin_amdgcn_s_setprio(1);
#pragma unroll
      for (int kh = 0; kh < 2; ++kh)
#pragma unroll
        for (int mm = 0; mm < 2; ++mm)
#pragma unroll
          for (int n = 0; n < 4; ++n)
            acc[2 * p + mm][n] = __builtin_amdgcn_mfma_f32_16x16x32_bf16(
                afr[mm][kh], bfrag[n][kh], acc[2 * p + mm][n], 0, 0, 0);
      __builtin_amdgcn_s_setprio(0);
      if (p == 0) __builtin_amdgcn_s_barrier();
      if (p == 3) {
        if (t < NT - 2)       asm volatile("s_waitcnt vmcnt(4)" ::: "memory");
        else if (t == NT - 2) asm volatile("s_waitcnt vmcnt(0)" ::: "memory");
        __builtin_amdgcn_s_barrier();
      }
    }
  }

  // EPI == 2: +bias, exact GELU -> bf16 [*, CF]
#pragma unroll
  for (int m = 0; m < 8; ++m) {
#pragma unroll
    for (int n = 0; n < 4; ++n) {
      const int col = colBase + wc * 64 + n * 16 + l15;
      const float bias = bias0[col];
#pragma unroll
      for (int fr = 0; fr < 4; ++fr) {
        const int row = rowBase + wr * 128 + m * 16 + lg * 4 + fr;
        const float v = acc[m][n][fr] + bias;
        const float gel = 0.5f * v * (1.0f + erff(v * 0.70710678118654752f));
        dst0[(size_t)row * CF + col] = __float2bfloat16(gel);
      }
    }
  }
}

// ---------------------------------------------------------------- attention
// R9/R13/R17 proven (best): block-staged flash attention, double-buffered
// K/V. grid 1536, head XCD-affinity (bh=(i&7)+8*(i>>7), qb=(i>>3)&15).
// 4 waves x 16 q-rows share K/V tiles staged via global_load_lds + T2
// swizzle; swapped QK^T, defer-max, per-lane lsum. Q pre-scaled 1/8.
__global__ __launch_bounds__(256) void attn_kernel(
    const bf16* __restrict__ Qb, const bf16* __restrict__ Kb,
    const bf16* __restrict__ Vtb, bf16* __restrict__ ctxb) {
  __shared__ __align__(16) bf16 Ks[2][64 * 64];  // [m][k-dim], 8 KB/buf
  __shared__ __align__(16) bf16 Vs[2][64 * 64];  // Vt tile [d][key], 8 KB/buf
  __shared__ __align__(16) bf16 Ps[4][16][72];   // per-wave P tile

  const int tid = threadIdx.x;
  const int w = tid >> 6, l = tid & 63;
  const int l15 = l & 15, lg = l >> 4;
  const int i = blockIdx.x;
  const int bh = (i & 7) + 8 * (i >> 7);  // head 0..95, fixed per XCD
  const int qb = (i >> 3) & 15;           // 64-row q block
  const int b = bh / CH, h = bh - b * CH;
  const bf16* Qh  = Qb  + (size_t)bh * CN * CK;
  const bf16* Kh  = Kb  + (size_t)bh * CN * CK;
  const bf16* Vth = Vtb + (size_t)bh * CK * CN;
  const int q0 = qb * 64 + w * 16;

  auto stageKV = [&](int kt, int buf) {
#pragma unroll
    for (int ii = 0; ii < 2; ++ii) {
      const int s = ii * 256 + w * 64 + l;
      const int row = s >> 3, c16 = s & 7;
      const int gc16 = c16 ^ (row & 7);
      gload_lds16(Kh + (size_t)(kt * 64 + row) * CK + gc16 * 8,
                  (void*)&Ks[buf][(ii * 256 + w * 64) * 8]);
      gload_lds16(Vth + (size_t)row * CN + kt * 64 + gc16 * 8,
                  (void*)&Vs[buf][(ii * 256 + w * 64) * 8]);
    }
  };
  auto read_k = [&](int buf, int mb, int c) -> short8 {
    const int row = mb * 16 + l15;
    const int c16 = (c * 4 + lg) ^ (l15 & 7);
    return *reinterpret_cast<const short8*>(&Ks[buf][row * 64 + c16 * 8]);
  };
  auto read_v = [&](int buf, int kb, int c) -> short8 {
    const int row = kb * 16 + l15;
    const int c16 = (c * 4 + lg) ^ (l15 & 7);
    return *reinterpret_cast<const short8*>(&Vs[buf][row * 64 + c16 * 8]);
  };

  short8 aq[2];
#pragma unroll
  for (int c = 0; c < 2; ++c)
    aq[c] = *reinterpret_cast<const short8*>(
        Qh + (size_t)(q0 + l15) * CK + c * 32 + lg * 8);

  f32x4 oacc[4];
  float mreg = -INFINITY, lpart = 0.f;
#pragma unroll
  for (int kb = 0; kb < 4; ++kb)
#pragma unroll
    for (int r = 0; r < 4; ++r) oacc[kb][r] = 0.f;

  stageKV(0, 0);
  asm volatile("s_waitcnt vmcnt(0)" ::: "memory");
  __builtin_amdgcn_s_barrier();

#pragma unroll 1
  for (int kt = 0; kt < 16; ++kt) {
    const int buf = kt & 1;
    if (kt < 15) stageKV(kt + 1, buf ^ 1);

    short8 kf[4][2];
#pragma unroll
    for (int mb = 0; mb < 4; ++mb)
#pragma unroll
      for (int c = 0; c < 2; ++c) kf[mb][c] = read_k(buf, mb, c);

    f32x4 sacc[4];
    __builtin_amdgcn_s_setprio(1);
#pragma unroll
    for (int mb = 0; mb < 4; ++mb) {
      f32x4 z;
#pragma unroll
      for (int r = 0; r < 4; ++r) z[r] = 0.f;
      z = __builtin_amdgcn_mfma_f32_16x16x32_bf16(kf[mb][0], aq[0], z, 0, 0, 0);
      z = __builtin_amdgcn_mfma_f32_16x16x32_bf16(kf[mb][1], aq[1], z, 0, 0, 0);
      sacc[mb] = z;
    }
    __builtin_amdgcn_s_setprio(0);

    float mx = sacc[0][0];
#pragma unroll
    for (int mb = 0; mb < 4; ++mb)
#pragma unroll
      for (int r = 0; r < 4; ++r) mx = fmaxf(mx, sacc[mb][r]);
    mx = fmaxf(mx, __shfl_xor(mx, 16));
    mx = fmaxf(mx, __shfl_xor(mx, 32));
    if (!__all(mx - mreg <= 8.f)) {
      const float mn = fmaxf(mreg, mx);
      const float alpha = __expf(mreg - mn);
      float alr[4];
#pragma unroll
      for (int r = 0; r < 4; ++r) alr[r] = __shfl(alpha, lg * 4 + r);
#pragma unroll
      for (int kb = 0; kb < 4; ++kb)
#pragma unroll
        for (int r = 0; r < 4; ++r) oacc[kb][r] *= alr[r];
      lpart *= alpha;
      mreg = mn;
    }
#pragma unroll
    for (int mb = 0; mb < 4; ++mb)
#pragma unroll
      for (int r = 0; r < 4; ++r) {
        const float p = __expf(sacc[mb][r] - mreg);
        sacc[mb][r] = p;
        lpart += p;
      }

    short8 vf[4][2];
#pragma unroll
    for (int kb = 0; kb < 4; ++kb)
#pragma unroll
      for (int c = 0; c < 2; ++c) vf[kb][c] = read_v(buf, kb, c);

#pragma unroll
    for (int mb = 0; mb < 4; ++mb) {
      bf16 tmp[4];
#pragma unroll
      for (int r = 0; r < 4; ++r) tmp[r] = __float2bfloat16(sacc[mb][r]);
      *reinterpret_cast<uint2*>(&Ps[w][l15][mb * 16 + lg * 4]) =
          *reinterpret_cast<const uint2*>(tmp);
    }
    const short8 pa0 = *reinterpret_cast<const short8*>(&Ps[w][l15][lg * 8]);
    const short8 pa1 = *reinterpret_cast<const short8*>(&Ps[w][l15][32 + lg * 8]);

    __builtin_amdgcn_s_setprio(1);
#pragma unroll
    for (int kb = 0; kb < 4; ++kb) {
      oacc[kb] = __builtin_amdgcn_mfma_f32_16x16x32_bf16(pa0, vf[kb][0],
                                                         oacc[kb], 0, 0, 0);
      oacc[kb] = __builtin_amdgcn_mfma_f32_16x16x32_bf16(pa1, vf[kb][1],
                                                         oacc[kb], 0, 0, 0);
    }
    __builtin_amdgcn_s_setprio(0);

    asm volatile("s_waitcnt vmcnt(0)" ::: "memory");
    __builtin_amdgcn_s_barrier();
  }

  float lsum = lpart;
  lsum += __shfl_xor(lsum, 16);
  lsum += __shfl_xor(lsum, 32);

#pragma unroll
  for (int r = 0; r < 4; ++r) {
    const float inv = 1.f / __shfl(lsum, lg * 4 + r);
    const int n = q0 + lg * 4 + r;
    bf16* dst = ctxb + ((size_t)(b * CN + n)) * CD + h * CK;
#pragma unroll
    for (int kb = 0; kb < 4; ++kb)
      dst[kb * 16 + l15] = __float2bfloat16(oacc[kb][r] * inv);
  }
}

// ---------------------------------------------------------------- launcher
extern "C" void kernel_launch(void* const* d_in, const int* in_sizes, int n_in,
                              void* d_out, int out_size, void* d_ws,
                              size_t ws_size, hipStream_t stream) {
  const float* x    = (const float*)d_in[0];
  const float* ln1g = (const float*)d_in[1];
  const float* ln1b = (const float*)d_in[2];
  const float* wq   = (const float*)d_in[3];
  const float* bq   = (const float*)d_in[4];
  const float* wk   = (const float*)d_in[5];
  const float* bk   = (const float*)d_in[6];
  const float* wv   = (const float*)d_in[7];
  const float* bv   = (const float*)d_in[8];
  const float* wo   = (const float*)d_in[9];
  const float* bo   = (const float*)d_in[10];
  const float* ln2g = (const float*)d_in[11];
  const float* ln2b = (const float*)d_in[12];
  const float* w1   = (const float*)d_in[13];
  const float* b1   = (const float*)d_in[14];
  const float* w2   = (const float*)d_in[15];
  const float* b2   = (const float*)d_in[16];

  char* ws = (char*)d_ws;
  bf16* wqkvt = (bf16*)(ws + 0);
  bf16* wot   = (bf16*)(ws + 3538944);
  bf16* w1t   = (bf16*)(ws + 4718592);
  bf16* w2t   = (bf16*)(ws + 9437184);
  bf16* h1    = (bf16*)(ws + 14155776);
  bf16* Qbuf  = (bf16*)(ws + 26738688);
  bf16* Kbuf  = (bf16*)(ws + 39321600);
  bf16* Vtbuf = (bf16*)(ws + 51904512);
  bf16* gb    = (bf16*)(ws + 14155776);  // reuse h1+Q+K+V region
  bf16* ctxb  = (bf16*)(ws + 64487424);
  bf16* h2    = (bf16*)(ws + 64487424);  // reuse ctx region
  float* outb = (float*)(ws + 77070336);
  float* y    = (float*)d_out;

  // weight prep: 4x 768x768 in one launch; wq scaled 1/8 inside
  transpose4_f32_bf16<<<dim3(24, 24, 4), 256, 0, stream>>>(
      wq, wk, wv, wo, wqkvt, wqkvt + 768 * 768, wqkvt + 2 * 768 * 768, wot);
  transpose_f32_bf16<<<dim3(96, 24), 256, 0, stream>>>(w1, w1t, 768, 3072, 1.f);
  transpose_f32_bf16<<<dim3(24, 96), 256, 0, stream>>>(w2, w2t, 3072, 768, 1.f);

  ln_bf16<<<ROWS, 256, 0, stream>>>(x, ln1g, ln1b, h1);

  // QKV: 128² m97 kernel (smooth multi-residency fill; R18 single-variable
  // test vs the 256² kernel's 288-block 2-round tail). grid 64x18 = 1152.
  gemm128_kernel<0><<<18 * (ROWS / 128), 256, 0, stream>>>(
      h1, wqkvt, 768, 18, nullptr, Qbuf, Kbuf, Vtbuf, bq, bk, bv, nullptr);

  attn_kernel<<<CB * CH * 16, 256, 0, stream>>>(Qbuf, Kbuf, Vtbuf, ctxb);

  gemm128_kernel<1><<<6 * (ROWS / 128), 256, 0, stream>>>(
      ctxb, wot, 768, 6, outb, nullptr, nullptr, nullptr, bo, nullptr, nullptr, x);

  ln_bf16<<<ROWS, 256, 0, stream>>>(outb, ln2g, ln2b, h2);

  // MLP1: 256² thin-barrier, grid 32x12 = 384 (%8==0)
  gemm256_kernel<2><<<(ROWS / 256) * 12, 512, 0, stream>>>(
      h2, w1t, 768, 12, gb, b1);

  gemm128_kernel<1><<<6 * (ROWS / 128), 256, 0, stream>>>(
      gb, w2t, 3072, 6, y, nullptr, nullptr, nullptr, b2, nullptr, nullptr, outb);

  (void)in_sizes; (void)n_in; (void)out_size; (void)ws_size;
}

// Round 19
// 325.127 us; speedup vs baseline: 1.0270x; 1.0270x over previous
//
#include <hip/hip_runtime.h>
#include <hip/hip_bf16.h>
#include <math.h>

typedef __hip_bfloat16 bf16;
typedef __attribute__((ext_vector_type(8))) short short8;   // 8 bf16 = 4 VGPRs
typedef __attribute__((ext_vector_type(4))) float f32x4;

#define DEV __device__ __forceinline__

// problem constants
constexpr int CB = 8, CN = 1024, CD = 768, CH = 12, CK = 64, CF = 3072;
constexpr int ROWS = CB * CN;  // 8192

// ---------------------------------------------------------------- utilities
DEV void gload_lds16(const void* g, void* l) {
  __builtin_amdgcn_global_load_lds(
      (const __attribute__((address_space(1))) void*)g,
      (__attribute__((address_space(3))) void*)l, 16, 0, 0);
}

// ------------------------------------------------- weight prep (T + cast)
// four 768x768 fp32 [R][C] -> bf16 [C][R]; z selects matrix; wq scaled 1/8.
__global__ __launch_bounds__(256) void transpose4_f32_bf16(
    const float* __restrict__ s0, const float* __restrict__ s1,
    const float* __restrict__ s2, const float* __restrict__ s3,
    bf16* __restrict__ d0, bf16* __restrict__ d1, bf16* __restrict__ d2,
    bf16* __restrict__ d3) {
  __shared__ float tile[32][33];
  const int z = blockIdx.z;
  const float* in = (z == 0) ? s0 : (z == 1) ? s1 : (z == 2) ? s2 : s3;
  bf16* out = (z == 0) ? d0 : (z == 1) ? d1 : (z == 2) ? d2 : d3;
  const float scale = (z == 0) ? 0.125f : 1.f;
  const int R = 768, C = 768;
  const int tx = threadIdx.x & 31, ty = threadIdx.x >> 5;  // 32 x 8
  const int c0 = blockIdx.x * 32, r0 = blockIdx.y * 32;
#pragma unroll
  for (int i = 0; i < 4; ++i)
    tile[ty + i * 8][tx] = in[(size_t)(r0 + ty + i * 8) * C + c0 + tx];
  __syncthreads();
#pragma unroll
  for (int i = 0; i < 4; ++i)
    out[(size_t)(c0 + ty + i * 8) * R + r0 + tx] =
        __float2bfloat16(tile[tx][ty + i * 8] * scale);
}

__global__ __launch_bounds__(256) void transpose_f32_bf16(
    const float* __restrict__ in, bf16* __restrict__ out, int R, int C,
    float scale) {
  __shared__ float tile[32][33];
  const int tx = threadIdx.x & 31, ty = threadIdx.x >> 5;  // 32 x 8
  const int c0 = blockIdx.x * 32, r0 = blockIdx.y * 32;
#pragma unroll
  for (int i = 0; i < 4; ++i)
    tile[ty + i * 8][tx] = in[(size_t)(r0 + ty + i * 8) * C + c0 + tx];
  __syncthreads();
#pragma unroll
  for (int i = 0; i < 4; ++i)
    out[(size_t)(c0 + ty + i * 8) * R + r0 + tx] =
        __float2bfloat16(tile[tx][ty + i * 8] * scale);
}

// ---------------------------------------------------------------- LayerNorm
__global__ __launch_bounds__(256) void ln_bf16(
    const float* __restrict__ in, const float* __restrict__ gamma,
    const float* __restrict__ beta, bf16* __restrict__ out) {
  const int row = blockIdx.x;
  const int tid = threadIdx.x;
  const float* x = in + (size_t)row * CD;
  const float v0 = x[tid], v1 = x[tid + 256], v2 = x[tid + 512];
  float s = v0 + v1 + v2;
  float q = v0 * v0 + v1 * v1 + v2 * v2;
#pragma unroll
  for (int off = 32; off > 0; off >>= 1) {
    s += __shfl_xor(s, off);
    q += __shfl_xor(q, off);
  }
  __shared__ float sm[8];
  const int w = tid >> 6, l = tid & 63;
  if (l == 0) { sm[w] = s; sm[4 + w] = q; }
  __syncthreads();
  s = sm[0] + sm[1] + sm[2] + sm[3];
  q = sm[4] + sm[5] + sm[6] + sm[7];
  const float mean = s * (1.f / CD);
  const float var = q * (1.f / CD) - mean * mean;
  const float rs = rsqrtf(var + 1e-5f);
  bf16* o = out + (size_t)row * CD;
  o[tid]       = __float2bfloat16((v0 - mean) * rs * gamma[tid]       + beta[tid]);
  o[tid + 256] = __float2bfloat16((v1 - mean) * rs * gamma[tid + 256] + beta[tid + 256]);
  o[tid + 512] = __float2bfloat16((v2 - mean) * rs * gamma[tid + 512] + beta[tid + 512]);
}

// ------------------------------------------- 256x256 GEMM, thin barriers
// R13/R17 proven: 4-phase, VGPR-112 no-spill, 2 barriers/K-tile.
// Stage slots: p0 A(t+1)h0, p1 A(t+1)h1, p2 B(t+2)h0, p3 B(t+2)h1.
// Mid-barrier after ph0 MFMA; tile-end vmcnt(4)+barrier. t==NT-2: vmcnt(0).
// T2 swizzle: inverse-swizzled GLOBAL source + swizzled ds_read (rule #21).
template <int EPI>
__global__ __launch_bounds__(512, 2) void gemm256_kernel(
    const bf16* __restrict__ A, const bf16* __restrict__ Bt, int Kd, int nbx,
    bf16* __restrict__ dst0, bf16* __restrict__ dst1, bf16* __restrict__ dst2,
    const float* __restrict__ bias0, const float* __restrict__ bias1,
    const float* __restrict__ bias2) {
  __shared__ __align__(16) bf16 As[2][2][128 * 64];  // 64 KB
  __shared__ __align__(16) bf16 Bs[2][2][128 * 64];  // 64 KB

  const int tid = threadIdx.x;
  const int w = tid >> 6, l = tid & 63;
  const int wr = w >> 2, wc = w & 3;  // 2 x 4 wave grid
  const int l15 = l & 15, lg = l >> 4;

  const int L = blockIdx.x;
  const int cpx = gridDim.x >> 3;
  const int g = (L & 7) * cpx + (L >> 3);   // XCD swizzle (grid % 8 == 0)
  const int by = g / nbx, bx = g - by * nbx;
  const int rowBase = by * 256, colBase = bx * 256;
  const bool vswap = (EPI == 0) && (colBase >= 2 * CD);
  const int NT = Kd >> 6;

  auto stage = [&](int t, int q) {
    const int buf = t & 1;
    const int half = q & 1;
    const bf16* src = (q < 2) ? A : Bt;
    const int base = ((q < 2) ? rowBase : colBase) + half * 128;
    const int k0 = t * 64;
    bf16* lds = (q < 2) ? &As[buf][half][0] : &Bs[buf][half][0];
#pragma unroll
    for (int i = 0; i < 2; ++i) {
      const int s = i * 512 + tid;           // 16B slot 0..1023
      const int row = s >> 3, c16 = s & 7;
      const int gc16 = c16 ^ (row & 7);      // inverse swizzle on source
      gload_lds16(src + (size_t)(base + row) * Kd + k0 + gc16 * 8,
                  (void*)&lds[(i * 512 + w * 64) * 8]);
    }
  };
  auto read_a = [&](int buf, int m, int kh) -> short8 {
    const int row = m * 16 + l15;
    const int c16 = (kh * 4 + lg) ^ (l15 & 7);  // swizzled read
    return *reinterpret_cast<const short8*>(&As[buf][wr][row * 64 + c16 * 8]);
  };
  auto read_b = [&](int buf, int n, int kh) -> short8 {
    const int c = wc * 64 + n * 16 + l15;
    const int half = c >> 7, row = c & 127;
    const int c16 = (kh * 4 + lg) ^ (l15 & 7);
    return *reinterpret_cast<const short8*>(&Bs[buf][half][row * 64 + c16 * 8]);
  };

  f32x4 acc[8][4];
#pragma unroll
  for (int m = 0; m < 8; ++m)
#pragma unroll
    for (int n = 0; n < 4; ++n)
#pragma unroll
      for (int r = 0; r < 4; ++r) acc[m][n][r] = 0.f;

  stage(0, 0); stage(0, 1); stage(0, 2); stage(0, 3);
  stage(1, 2); stage(1, 3);
  asm volatile("s_waitcnt vmcnt(4)" ::: "memory");
  __builtin_amdgcn_s_barrier();

  short8 bfrag[4][2];
  for (int t = 0; t < NT; ++t) {
    const int buf = t & 1;
#pragma unroll
    for (int p = 0; p < 4; ++p) {
      short8 afr[2][2];
      if (p == 0) {
#pragma unroll
        for (int n = 0; n < 4; ++n)
#pragma unroll
          for (int kh = 0; kh < 2; ++kh) bfrag[n][kh] = read_b(buf, n, kh);
      }
#pragma unroll
      for (int mm = 0; mm < 2; ++mm)
#pragma unroll
        for (int kh = 0; kh < 2; ++kh) afr[mm][kh] = read_a(buf, 2 * p + mm, kh);
      if (p == 0 && t + 1 < NT) stage(t + 1, 0);
      if (p == 1 && t + 1 < NT) stage(t + 1, 1);
      if (p == 2 && t + 2 < NT) stage(t + 2, 2);
      if (p == 3 && t + 2 < NT) stage(t + 2, 3);
      __builtin_amdgcn_s_setprio(1);
      if (!vswap) {
#pragma unroll
        for (int kh = 0; kh < 2; ++kh)
#pragma unroll
          for (int mm = 0; mm < 2; ++mm)
#pragma unroll
            for (int n = 0; n < 4; ++n)
              acc[2 * p + mm][n] = __builtin_amdgcn_mfma_f32_16x16x32_bf16(
                  afr[mm][kh], bfrag[n][kh], acc[2 * p + mm][n], 0, 0, 0);
      } else {
#pragma unroll
        for (int kh = 0; kh < 2; ++kh)
#pragma unroll
          for (int mm = 0; mm < 2; ++mm)
#pragma unroll
            for (int n = 0; n < 4; ++n)
              acc[2 * p + mm][n] = __builtin_amdgcn_mfma_f32_16x16x32_bf16(
                  bfrag[n][kh], afr[mm][kh], acc[2 * p + mm][n], 0, 0, 0);
      }
      __builtin_amdgcn_s_setprio(0);
      if (p == 0) __builtin_amdgcn_s_barrier();
      if (p == 3) {
        if (t < NT - 2)       asm volatile("s_waitcnt vmcnt(4)" ::: "memory");
        else if (t == NT - 2) asm volatile("s_waitcnt vmcnt(0)" ::: "memory");
        __builtin_amdgcn_s_barrier();
      }
    }
  }

  if constexpr (EPI == 0) {
    if (vswap) {
#pragma unroll
      for (int m = 0; m < 8; ++m) {
        const int nrow = rowBase + wr * 128 + m * 16 + l15;
        const int b = nrow >> 10, nn = nrow & 1023;
#pragma unroll
        for (int n = 0; n < 4; ++n) {
#pragma unroll
          for (int fr = 0; fr < 4; ++fr) {
            const int hk = (colBase - 2 * CD) + wc * 64 + n * 16 + lg * 4 + fr;
            const float v = acc[m][n][fr] + bias2[hk];
            const int h = hk >> 6, kk = hk & 63;
            dst2[((size_t)(b * CH + h) * CK + kk) * CN + nn] = __float2bfloat16(v);
          }
        }
      }
    } else {
      const int which = colBase / CD;  // 0=Q, 1=K
#pragma unroll
      for (int m = 0; m < 8; ++m) {
#pragma unroll
        for (int n = 0; n < 4; ++n) {
          const int col = colBase + wc * 64 + n * 16 + l15;
          const int hk = col - which * CD;
          const float bias = (which == 0) ? bias0[hk] * 0.125f : bias1[hk];
          bf16* dst = (which == 0) ? dst0 : dst1;
          const int h = hk >> 6, kk = hk & 63;
#pragma unroll
          for (int fr = 0; fr < 4; ++fr) {
            const int row = rowBase + wr * 128 + m * 16 + lg * 4 + fr;
            const int b = row >> 10, nn = row & 1023;
            dst[(((size_t)(b * CH + h)) * CN + nn) * CK + kk] =
                __float2bfloat16(acc[m][n][fr] + bias);
          }
        }
      }
    }
  } else {  // EPI == 2: +bias, exact GELU -> bf16 [*, CF]
#pragma unroll
    for (int m = 0; m < 8; ++m) {
#pragma unroll
      for (int n = 0; n < 4; ++n) {
        const int col = colBase + wc * 64 + n * 16 + l15;
        const float bias = bias0[col];
#pragma unroll
        for (int fr = 0; fr < 4; ++fr) {
          const int row = rowBase + wr * 128 + m * 16 + lg * 4 + fr;
          const float v = acc[m][n][fr] + bias;
          const float gel = 0.5f * v * (1.0f + erff(v * 0.70710678118654752f));
          dst0[(size_t)row * CF + col] = __float2bfloat16(gel);
        }
      }
    }
  }
}

// ---------------------------------------------------------------- GEMM 128²
// (m97 structure, for the narrow N=768 GEMMs). EPI 1: +bias +resid, fp32 out.
__global__ __launch_bounds__(256) void gemm128_res_kernel(
    const bf16* __restrict__ A, const bf16* __restrict__ Bt, int Kd, int nbx,
    float* __restrict__ outF, const float* __restrict__ bias0,
    const float* __restrict__ resid) {
  __shared__ __align__(16) bf16 As[128 * 32];
  __shared__ __align__(16) bf16 Bs[128 * 32];
  const int tid = threadIdx.x;
  const int w = tid >> 6, l = tid & 63;
  const int wr = w >> 1, wc = w & 1;
  const int l15 = l & 15, lg = l >> 4;
  const int L = blockIdx.x;
  const int cpx = gridDim.x >> 3;
  const int g = (L & 7) * cpx + (L >> 3);
  const int by = g / nbx, bx = g - by * nbx;
  const int rowBase = by * 128;
  const int colBase = bx * 128;

  f32x4 acc[4][4];
#pragma unroll
  for (int i = 0; i < 4; ++i)
#pragma unroll
    for (int j = 0; j < 4; ++j)
#pragma unroll
      for (int r = 0; r < 4; ++r) acc[i][j][r] = 0.f;

  for (int k0 = 0; k0 < Kd; k0 += 32) {
    __syncthreads();
#pragma unroll
    for (int i = 0; i < 2; ++i) {
      const int c = w * 128 + i * 64 + l;
      const int r = c >> 2, cc = c & 3;
      gload_lds16(A + (size_t)(rowBase + r) * Kd + k0 + cc * 8,
                  (void*)&As[(w * 128 + i * 64) * 8]);
      gload_lds16(Bt + (size_t)(colBase + r) * Kd + k0 + cc * 8,
                  (void*)&Bs[(w * 128 + i * 64) * 8]);
    }
    __syncthreads();
    short8 af[4], bfr[4];
#pragma unroll
    for (int fm = 0; fm < 4; ++fm)
      af[fm] = *reinterpret_cast<const short8*>(
          &As[(wr * 64 + fm * 16 + l15) * 32 + lg * 8]);
#pragma unroll
    for (int fn = 0; fn < 4; ++fn)
      bfr[fn] = *reinterpret_cast<const short8*>(
          &Bs[(wc * 64 + fn * 16 + l15) * 32 + lg * 8]);
#pragma unroll
    for (int fm = 0; fm < 4; ++fm)
#pragma unroll
      for (int fn = 0; fn < 4; ++fn)
        acc[fm][fn] = __builtin_amdgcn_mfma_f32_16x16x32_bf16(
            af[fm], bfr[fn], acc[fm][fn], 0, 0, 0);
  }

  const int mrow0 = rowBase + wr * 64;
  const int ncol0 = colBase + wc * 64;
#pragma unroll
  for (int fm = 0; fm < 4; ++fm) {
#pragma unroll
    for (int fn = 0; fn < 4; ++fn) {
      const int col = ncol0 + fn * 16 + l15;
#pragma unroll
      for (int fr = 0; fr < 4; ++fr) {
        const int row = mrow0 + fm * 16 + lg * 4 + fr;
        float v = acc[fm][fn][fr];
        v += bias0[col] + resid[(size_t)row * CD + col];
        outF[(size_t)row * CD + col] = v;
      }
    }
  }
}

// ---------------------------------------------------------------- attention
// R9/R13/R17 proven (best): block-staged flash attention, DOUBLE-buffered K/V.
// grid 1536, head XCD-affinity (bh=(i&7)+8*(i>>7), qb=(i>>3)&15). 4 waves x
// 16 q-rows share K/V tiles staged via global_load_lds + T2 swizzle;
// swapped QK^T, defer-max, per-lane lsum. Q pre-scaled 1/8.
__global__ __launch_bounds__(256) void attn_kernel(
    const bf16* __restrict__ Qb, const bf16* __restrict__ Kb,
    const bf16* __restrict__ Vtb, bf16* __restrict__ ctxb) {
  __shared__ __align__(16) bf16 Ks[2][64 * 64];  // [m][k-dim], 8 KB/buf
  __shared__ __align__(16) bf16 Vs[2][64 * 64];  // Vt tile [d][key], 8 KB/buf
  __shared__ __align__(16) bf16 Ps[4][16][72];   // per-wave P tile

  const int tid = threadIdx.x;
  const int w = tid >> 6, l = tid & 63;
  const int l15 = l & 15, lg = l >> 4;
  const int i = blockIdx.x;
  const int bh = (i & 7) + 8 * (i >> 7);  // head 0..95, fixed per XCD
  const int qb = (i >> 3) & 15;           // 64-row q block
  const int b = bh / CH, h = bh - b * CH;
  const bf16* Qh  = Qb  + (size_t)bh * CN * CK;
  const bf16* Kh  = Kb  + (size_t)bh * CN * CK;
  const bf16* Vth = Vtb + (size_t)bh * CK * CN;
  const int q0 = qb * 64 + w * 16;

  auto stageKV = [&](int kt, int buf) {
#pragma unroll
    for (int ii = 0; ii < 2; ++ii) {
      const int s = ii * 256 + w * 64 + l;
      const int row = s >> 3, c16 = s & 7;
      const int gc16 = c16 ^ (row & 7);
      gload_lds16(Kh + (size_t)(kt * 64 + row) * CK + gc16 * 8,
                  (void*)&Ks[buf][(ii * 256 + w * 64) * 8]);
      gload_lds16(Vth + (size_t)row * CN + kt * 64 + gc16 * 8,
                  (void*)&Vs[buf][(ii * 256 + w * 64) * 8]);
    }
  };
  auto read_k = [&](int buf, int mb, int c) -> short8 {
    const int row = mb * 16 + l15;
    const int c16 = (c * 4 + lg) ^ (l15 & 7);
    return *reinterpret_cast<const short8*>(&Ks[buf][row * 64 + c16 * 8]);
  };
  auto read_v = [&](int buf, int kb, int c) -> short8 {
    const int row = kb * 16 + l15;
    const int c16 = (c * 4 + lg) ^ (l15 & 7);
    return *reinterpret_cast<const short8*>(&Vs[buf][row * 64 + c16 * 8]);
  };

  short8 aq[2];
#pragma unroll
  for (int c = 0; c < 2; ++c)
    aq[c] = *reinterpret_cast<const short8*>(
        Qh + (size_t)(q0 + l15) * CK + c * 32 + lg * 8);

  f32x4 oacc[4];
  float mreg = -INFINITY, lpart = 0.f;
#pragma unroll
  for (int kb = 0; kb < 4; ++kb)
#pragma unroll
    for (int r = 0; r < 4; ++r) oacc[kb][r] = 0.f;

  stageKV(0, 0);
  asm volatile("s_waitcnt vmcnt(0)" ::: "memory");
  __builtin_amdgcn_s_barrier();

#pragma unroll 1
  for (int kt = 0; kt < 16; ++kt) {
    const int buf = kt & 1;
    if (kt < 15) stageKV(kt + 1, buf ^ 1);

    short8 kf[4][2];
#pragma unroll
    for (int mb = 0; mb < 4; ++mb)
#pragma unroll
      for (int c = 0; c < 2; ++c) kf[mb][c] = read_k(buf, mb, c);

    f32x4 sacc[4];
    __builtin_amdgcn_s_setprio(1);
#pragma unroll
    for (int mb = 0; mb < 4; ++mb) {
      f32x4 z;
#pragma unroll
      for (int r = 0; r < 4; ++r) z[r] = 0.f;
      z = __builtin_amdgcn_mfma_f32_16x16x32_bf16(kf[mb][0], aq[0], z, 0, 0, 0);
      z = __builtin_amdgcn_mfma_f32_16x16x32_bf16(kf[mb][1], aq[1], z, 0, 0, 0);
      sacc[mb] = z;
    }
    __builtin_amdgcn_s_setprio(0);

    float mx = sacc[0][0];
#pragma unroll
    for (int mb = 0; mb < 4; ++mb)
#pragma unroll
      for (int r = 0; r < 4; ++r) mx = fmaxf(mx, sacc[mb][r]);
    mx = fmaxf(mx, __shfl_xor(mx, 16));
    mx = fmaxf(mx, __shfl_xor(mx, 32));
    if (!__all(mx - mreg <= 8.f)) {
      const float mn = fmaxf(mreg, mx);
      const float alpha = __expf(mreg - mn);
      float alr[4];
#pragma unroll
      for (int r = 0; r < 4; ++r) alr[r] = __shfl(alpha, lg * 4 + r);
#pragma unroll
      for (int kb = 0; kb < 4; ++kb)
#pragma unroll
        for (int r = 0; r < 4; ++r) oacc[kb][r] *= alr[r];
      lpart *= alpha;
      mreg = mn;
    }
#pragma unroll
    for (int mb = 0; mb < 4; ++mb)
#pragma unroll
      for (int r = 0; r < 4; ++r) {
        const float p = __expf(sacc[mb][r] - mreg);
        sacc[mb][r] = p;
        lpart += p;
      }

    short8 vf[4][2];
#pragma unroll
    for (int kb = 0; kb < 4; ++kb)
#pragma unroll
      for (int c = 0; c < 2; ++c) vf[kb][c] = read_v(buf, kb, c);

#pragma unroll
    for (int mb = 0; mb < 4; ++mb) {
      bf16 tmp[4];
#pragma unroll
      for (int r = 0; r < 4; ++r) tmp[r] = __float2bfloat16(sacc[mb][r]);
      *reinterpret_cast<uint2*>(&Ps[w][l15][mb * 16 + lg * 4]) =
          *reinterpret_cast<const uint2*>(tmp);
    }
    const short8 pa0 = *reinterpret_cast<const short8*>(&Ps[w][l15][lg * 8]);
    const short8 pa1 = *reinterpret_cast<const short8*>(&Ps[w][l15][32 + lg * 8]);

    __builtin_amdgcn_s_setprio(1);
#pragma unroll
    for (int kb = 0; kb < 4; ++kb) {
      oacc[kb] = __builtin_amdgcn_mfma_f32_16x16x32_bf16(pa0, vf[kb][0],
                                                         oacc[kb], 0, 0, 0);
      oacc[kb] = __builtin_amdgcn_mfma_f32_16x16x32_bf16(pa1, vf[kb][1],
                                                         oacc[kb], 0, 0, 0);
    }
    __builtin_amdgcn_s_setprio(0);

    asm volatile("s_waitcnt vmcnt(0)" ::: "memory");
    __builtin_amdgcn_s_barrier();
  }

  float lsum = lpart;
  lsum += __shfl_xor(lsum, 16);
  lsum += __shfl_xor(lsum, 32);

#pragma unroll
  for (int r = 0; r < 4; ++r) {
    const float inv = 1.f / __shfl(lsum, lg * 4 + r);
    const int n = q0 + lg * 4 + r;
    bf16* dst = ctxb + ((size_t)(b * CN + n)) * CD + h * CK;
#pragma unroll
    for (int kb = 0; kb < 4; ++kb)
      dst[kb * 16 + l15] = __float2bfloat16(oacc[kb][r] * inv);
  }
}

// ---------------------------------------------------------------- launcher
extern "C" void kernel_launch(void* const* d_in, const int* in_sizes, int n_in,
                              void* d_out, int out_size, void* d_ws,
                              size_t ws_size, hipStream_t stream) {
  const float* x    = (const float*)d_in[0];
  const float* ln1g = (const float*)d_in[1];
  const float* ln1b = (const float*)d_in[2];
  const float* wq   = (const float*)d_in[3];
  const float* bq   = (const float*)d_in[4];
  const float* wk   = (const float*)d_in[5];
  const float* bk   = (const float*)d_in[6];
  const float* wv   = (const float*)d_in[7];
  const float* bv   = (const float*)d_in[8];
  const float* wo   = (const float*)d_in[9];
  const float* bo   = (const float*)d_in[10];
  const float* ln2g = (const float*)d_in[11];
  const float* ln2b = (const float*)d_in[12];
  const float* w1   = (const float*)d_in[13];
  const float* b1   = (const float*)d_in[14];
  const float* w2   = (const float*)d_in[15];
  const float* b2   = (const float*)d_in[16];

  char* ws = (char*)d_ws;
  bf16* wqkvt = (bf16*)(ws + 0);
  bf16* wot   = (bf16*)(ws + 3538944);
  bf16* w1t   = (bf16*)(ws + 4718592);
  bf16* w2t   = (bf16*)(ws + 9437184);
  bf16* h1    = (bf16*)(ws + 14155776);
  bf16* Qbuf  = (bf16*)(ws + 26738688);
  bf16* Kbuf  = (bf16*)(ws + 39321600);
  bf16* Vtbuf = (bf16*)(ws + 51904512);
  bf16* gb    = (bf16*)(ws + 14155776);  // reuse h1+Q+K+V region
  bf16* ctxb  = (bf16*)(ws + 64487424);
  bf16* h2    = (bf16*)(ws + 64487424);  // reuse ctx region
  float* outb = (float*)(ws + 77070336);
  float* y    = (float*)d_out;

  // weight prep: 4x 768x768 in one launch; wq scaled 1/8 inside
  transpose4_f32_bf16<<<dim3(24, 24, 4), 256, 0, stream>>>(
      wq, wk, wv, wo, wqkvt, wqkvt + 768 * 768, wqkvt + 2 * 768 * 768, wot);
  transpose_f32_bf16<<<dim3(96, 24), 256, 0, stream>>>(w1, w1t, 768, 3072, 1.f);
  transpose_f32_bf16<<<dim3(24, 96), 256, 0, stream>>>(w2, w2t, 3072, 768, 1.f);

  ln_bf16<<<ROWS, 256, 0, stream>>>(x, ln1g, ln1b, h1);

  // QKV: 256² thin-barrier, grid 32x9 = 288 (%8==0)
  gemm256_kernel<0><<<(ROWS / 256) * 9, 512, 0, stream>>>(
      h1, wqkvt, 768, 9, Qbuf, Kbuf, Vtbuf, bq, bk, bv);

  attn_kernel<<<CB * CH * 16, 256, 0, stream>>>(Qbuf, Kbuf, Vtbuf, ctxb);

  gemm128_res_kernel<<<6 * (ROWS / 128), 256, 0, stream>>>(
      ctxb, wot, 768, 6, outb, bo, x);

  ln_bf16<<<ROWS, 256, 0, stream>>>(outb, ln2g, ln2b, h2);

  // MLP1: 256² thin-barrier, grid 32x12 = 384 (%8==0)
  gemm256_kernel<2><<<(ROWS / 256) * 12, 512, 0, stream>>>(
      h2, w1t, 768, 12, gb, nullptr, nullptr, b1, nullptr, nullptr);

  gemm128_res_kernel<<<6 * (ROWS / 128), 256, 0, stream>>>(
      gb, w2t, 3072, 6, y, b2, outb);

  (void)in_sizes; (void)n_in; (void)out_size; (void)ws_size;
}